// Round 3
// baseline (303.450 us; speedup 1.0000x reference)
//
#include <hip/hip_runtime.h>
#include <hip/hip_bf16.h>
#include <cstdint>

#define D_IN  4096
#define D_OUT 4096

typedef __attribute__((ext_vector_type(8))) __bf16 bf16x8;
typedef __attribute__((ext_vector_type(4))) float  f32x4;

typedef const __attribute__((address_space(1))) unsigned g_u32;
typedef __attribute__((address_space(3))) unsigned       l_u32;

__device__ __forceinline__ unsigned short f32_to_bf16_bits(float f) {
    union { float f; unsigned u; } v; v.f = f;
    unsigned r = v.u + 0x7fffu + ((v.u >> 16) & 1u);   // RNE
    return (unsigned short)(r >> 16);
}

// ---------------- pass 1: quantize x (scalar maxabs) and convert to bf16 ----
__global__ void quant_x_kernel(const float* __restrict__ x,
                               unsigned short* __restrict__ xq,
                               const float* __restrict__ xscale, int n) {
    int i = (blockIdx.x * blockDim.x + threadIdx.x) * 4;
    if (i >= n) return;
    float s    = fmaxf(xscale[0], 1e-8f);
    float step = s * (1.0f / 127.0f);
    float inv  = 127.0f / s;
    float4 v = *(const float4*)(x + i);
    ushort4 o;
    o.x = f32_to_bf16_bits(fminf(fmaxf(rintf(v.x * inv), -127.f), 127.f) * step);
    o.y = f32_to_bf16_bits(fminf(fmaxf(rintf(v.y * inv), -127.f), 127.f) * step);
    o.z = f32_to_bf16_bits(fminf(fmaxf(rintf(v.z * inv), -127.f), 127.f) * step);
    o.w = f32_to_bf16_bits(fminf(fmaxf(rintf(v.w * inv), -127.f), 127.f) * step);
    *(ushort4*)(xq + i) = o;
}

// ---------------- pass 2: convert W (K x N) to bf16, transposed -> Wt (N x K)
__global__ void convW_kernel(const float* __restrict__ W,
                             unsigned short* __restrict__ Wt) {
    __shared__ float tile[32][33];
    int n0 = blockIdx.x * 32, k0 = blockIdx.y * 32;
    tile[threadIdx.y][threadIdx.x] =
        W[(size_t)(k0 + threadIdx.y) * D_OUT + n0 + threadIdx.x];
    __syncthreads();
    Wt[(size_t)(n0 + threadIdx.y) * D_IN + k0 + threadIdx.x] =
        f32_to_bf16_bits(tile[threadIdx.x][threadIdx.y]);
}

// ---------------- pass 3: 256x256 bf16 GEMM, 2-region K-tile ---------------
// A : [M][K] bf16, Bt : [N][K] bf16, C : [M][N] f32
// Per K-tile t, TWO barrier regions:
//  R1 (compute): barrier | STAGE B1(t+1)->nxt | ds_read b01,a03,b23 | Q1,Q2
//                | ds_read a47 (reuse regs) | Q3,Q4   (compiler interleaves
//                reads with MFMAs via precise per-use lgkmcnt waits)
//  R2 (publish): barrier | STAGE B0(t+2),A(t+2)->cur | s_waitcnt vmcnt(6)
// vmcnt(6) drains exactly tile t+1's 8 loads (queue: <=14 outstanding).
// Safety: every ds_read of a region drains before its last MFMA use (auto
// waitcnt), hence before the barrier preceding the overwriting STAGE.
__global__ __launch_bounds__(512, 2)
void gemm_kernel(const unsigned short* __restrict__ A,
                 const unsigned short* __restrict__ Bt,
                 const float* __restrict__ bias,
                 float* __restrict__ C, int M) {
    constexpr int K = D_IN, N = D_OUT, BK = 64;
    constexpr int NT = K / BK;                 // 64 K-tiles
    __shared__ unsigned short lds[2 * 32768];  // 2 x (A 32KiB + B 32KiB) = 128 KiB

    const int tid  = threadIdx.x;
    const int lane = tid & 63;
    const int wid  = tid >> 6;
    const int wr   = wid >> 2;                 // 0..1  (M)
    const int wc   = wid & 3;                  // 0..3  (N)

    // bijective XCD-aware block swizzle
    const int nTn = N / 256;
    const int nwg = gridDim.x;
    int bid = blockIdx.x;
    int q8 = nwg >> 3, r8 = nwg & 7;
    int xcd = bid & 7, idx = bid >> 3;
    int swz = (xcd < r8 ? xcd * (q8 + 1) : r8 * (q8 + 1) + (xcd - r8) * q8) + idx;
    const int tm = swz / nTn, tn = swz % nTn;
    const int row0 = tm * 256, col0 = tn * 256;

    // staging chunk offsets. LDS dest stays LINEAR (chunk p = (i*512+tid)*16);
    // the XOR swizzle sw = p ^ ((p>>7)&7)<<4 is applied to the global SOURCE,
    // so physical LDS chunk p holds logical bytes sw(p) (involution).
    int srcOff[4], dstOff[4];
#pragma unroll
    for (int i = 0; i < 4; ++i) {
        int p  = (i * 512 + tid) * 16;
        int sw = p ^ (((p >> 7) & 7) << 4);
        dstOff[i] = p;
        srcOff[i] = (sw >> 7) * (K * 2) + (sw & 127);
    }

    const char* srcA = (const char*)(A  + (size_t)row0 * K);
    const char* srcB = (const char*)(Bt + (size_t)col0 * K);
    char* ldsb = (char*)lds;

    auto STAGE4 = [&](const char* src, char* dst) {
#pragma unroll
        for (int i = 0; i < 4; ++i)
            __builtin_amdgcn_global_load_lds((g_u32*)(src + srcOff[i]),
                                             (l_u32*)(dst + dstOff[i]), 16, 0, 0);
    };
    auto STAGE2 = [&](const char* src, char* dst) {
#pragma unroll
        for (int i = 0; i < 2; ++i)
            __builtin_amdgcn_global_load_lds((g_u32*)(src + srcOff[i]),
                                             (l_u32*)(dst + dstOff[i]), 16, 0, 0);
    };

    // ---- prologue: tile0 full (8 loads) + tile1 {B0, A} (6 loads) ----
    STAGE2(srcB, ldsb + 32768);                           // B0(0) -> buf0
    STAGE4(srcA, ldsb);                                   // A(0)  -> buf0
    STAGE2(srcB + 128 * K * 2, ldsb + 32768 + 16384);     // B1(0) -> buf0
    STAGE2(srcB + 128,           ldsb + 65536 + 32768);   // B0(1) -> buf1
    STAGE4(srcA + 128,           ldsb + 65536);           // A(1)  -> buf1

    f32x4 acc[8][4];
#pragma unroll
    for (int m = 0; m < 8; ++m)
#pragma unroll
        for (int n = 0; n < 4; ++n) acc[m][n] = (f32x4){0.f, 0.f, 0.f, 0.f};

    // swizzled per-lane read bases (row&7 == lane&7 for all our frag rows)
    const int cp0 = (((lane >> 4) << 4)) ^ ((lane & 7) << 4);
    const int cp1 = cp0 ^ 64;
    const int aBase = (wr * 128 + (lane & 15)) * 128;     // bytes in A region
    const int bBase = (wc * 64  + (lane & 15)) * 128;     // bytes in B region

    asm volatile("s_waitcnt vmcnt(6)" ::: "memory");      // tile0 resident

    auto KITER = [&](int t, char* cur, char* nxt) {
        bf16x8 a[4][2], b01[2][2], b23[2][2];
        const char* cA = cur;
        const char* cB = cur + 32768;

        // ================= region 1: compute =================
        __builtin_amdgcn_s_barrier();
        if (t + 1 < NT) STAGE2(srcB + 128 * K * 2 + (t + 1) * 128, nxt + 32768 + 16384);

        // operand reads for Q1/Q2 (issue early; complete under MFMAs)
#pragma unroll
        for (int n = 0; n < 2; ++n) {
            b01[n][0] = *(const bf16x8*)(cB + bBase + n * 2048 + cp0);
            b01[n][1] = *(const bf16x8*)(cB + bBase + n * 2048 + cp1);
        }
#pragma unroll
        for (int m = 0; m < 4; ++m) {
            a[m][0] = *(const bf16x8*)(cA + aBase + m * 2048 + cp0);
            a[m][1] = *(const bf16x8*)(cA + aBase + m * 2048 + cp1);
        }
#pragma unroll
        for (int n = 0; n < 2; ++n) {
            b23[n][0] = *(const bf16x8*)(cB + bBase + 4096 + n * 2048 + cp0);
            b23[n][1] = *(const bf16x8*)(cB + bBase + 4096 + n * 2048 + cp1);
        }

        __builtin_amdgcn_s_setprio(1);
        // Q1: (m0-3, n0-1)
#pragma unroll
        for (int m = 0; m < 4; ++m)
#pragma unroll
            for (int n = 0; n < 2; ++n) {
                acc[m][n] = __builtin_amdgcn_mfma_f32_16x16x32_bf16(a[m][0], b01[n][0], acc[m][n], 0, 0, 0);
                acc[m][n] = __builtin_amdgcn_mfma_f32_16x16x32_bf16(a[m][1], b01[n][1], acc[m][n], 0, 0, 0);
            }
        // Q2: (m0-3, n2-3)
#pragma unroll
        for (int m = 0; m < 4; ++m)
#pragma unroll
            for (int n = 0; n < 2; ++n) {
                acc[m][n + 2] = __builtin_amdgcn_mfma_f32_16x16x32_bf16(a[m][0], b23[n][0], acc[m][n + 2], 0, 0, 0);
                acc[m][n + 2] = __builtin_amdgcn_mfma_f32_16x16x32_bf16(a[m][1], b23[n][1], acc[m][n + 2], 0, 0, 0);
            }
        // reload A rows 4-7 into the same registers (keeps VGPR budget)
#pragma unroll
        for (int m = 0; m < 4; ++m) {
            a[m][0] = *(const bf16x8*)(cA + aBase + 8192 + m * 2048 + cp0);
            a[m][1] = *(const bf16x8*)(cA + aBase + 8192 + m * 2048 + cp1);
        }
        // Q3: (m4-7, n2-3)
#pragma unroll
        for (int m = 0; m < 4; ++m)
#pragma unroll
            for (int n = 0; n < 2; ++n) {
                acc[m + 4][n + 2] = __builtin_amdgcn_mfma_f32_16x16x32_bf16(a[m][0], b23[n][0], acc[m + 4][n + 2], 0, 0, 0);
                acc[m + 4][n + 2] = __builtin_amdgcn_mfma_f32_16x16x32_bf16(a[m][1], b23[n][1], acc[m + 4][n + 2], 0, 0, 0);
            }
        // Q4: (m4-7, n0-1)
#pragma unroll
        for (int m = 0; m < 4; ++m)
#pragma unroll
            for (int n = 0; n < 2; ++n) {
                acc[m + 4][n] = __builtin_amdgcn_mfma_f32_16x16x32_bf16(a[m][0], b01[n][0], acc[m + 4][n], 0, 0, 0);
                acc[m + 4][n] = __builtin_amdgcn_mfma_f32_16x16x32_bf16(a[m][1], b01[n][1], acc[m + 4][n], 0, 0, 0);
            }
        __builtin_amdgcn_s_setprio(0);

        // ================= region 2: publish =================
        __builtin_amdgcn_s_barrier();
        if (t + 2 < NT) {
            STAGE2(srcB + (t + 2) * 128, cur + 32768);    // B0(t+2) -> cur
            STAGE4(srcA + (t + 2) * 128, cur);            // A (t+2) -> cur
            asm volatile("s_waitcnt vmcnt(6)" ::: "memory");   // tile t+1 resident
        } else {
            asm volatile("s_waitcnt vmcnt(0)" ::: "memory");
        }
    };

    for (int t = 0; t < NT; t += 2) {
        KITER(t,     ldsb,         ldsb + 65536);
        KITER(t + 1, ldsb + 65536, ldsb);
    }

    // ---- epilogue: C = acc + bias ----
    const int lr = (lane >> 4) * 4, lc = lane & 15;
#pragma unroll
    for (int n = 0; n < 4; ++n) {
        int col = col0 + wc * 64 + n * 16 + lc;
        float bv = bias[col];
#pragma unroll
        for (int m = 0; m < 8; ++m) {
            int rowb = row0 + wr * 128 + m * 16 + lr;
            f32x4 v = acc[m][n];
#pragma unroll
            for (int r2 = 0; r2 < 4; ++r2)
                C[(size_t)(rowb + r2) * N + col] = v[r2] + bv;
        }
    }
}

extern "C" void kernel_launch(void* const* d_in, const int* in_sizes, int n_in,
                              void* d_out, int out_size, void* d_ws, size_t ws_size,
                              hipStream_t stream) {
    const float* x      = (const float*)d_in[0];   // [4,2048,4096] f32
    const float* W      = (const float*)d_in[1];   // [4096,4096] f32
    const float* xscale = (const float*)d_in[2];   // scalar
    const float* bias   = (const float*)d_in[3];   // [4096] f32
    float* out = (float*)d_out;

    const int nx = in_sizes[0];            // 33554432
    const int M  = nx / D_IN;              // 8192

    unsigned short* xq = (unsigned short*)d_ws;                           // 64 MiB
    unsigned short* Wt = (unsigned short*)((char*)d_ws + (size_t)nx * 2); // 32 MiB

    quant_x_kernel<<<nx / 4 / 256, 256, 0, stream>>>(x, xq, xscale, nx);

    dim3 tb(32, 32);
    dim3 tg(D_OUT / 32, D_IN / 32);
    convW_kernel<<<tg, tb, 0, stream>>>(W, Wt);

    int grid = (M / 256) * (D_OUT / 256);  // 512
    gemm_kernel<<<grid, 512, 0, stream>>>(xq, Wt, bias, out, M);
}

// Round 4
// 209.896 us; speedup vs baseline: 1.4457x; 1.4457x over previous
//
#include <hip/hip_runtime.h>
#include <hip/hip_bf16.h>
#include <cstdint>

#define D_IN  4096
#define D_OUT 4096

typedef __attribute__((ext_vector_type(4))) int   i32x4;
typedef __attribute__((ext_vector_type(4))) float f32x4;

typedef const __attribute__((address_space(1))) unsigned g_u32;
typedef __attribute__((address_space(3))) unsigned       l_u32;

// ---------------- pass 0a: per-block max|W| --------------------------------
__global__ void wmax1_kernel(const float* __restrict__ W,
                             float* __restrict__ bmax, int n) {
    __shared__ float red[256];
    int tid = threadIdx.x;
    float m = 0.f;
    for (int i = (blockIdx.x * 256 + tid) * 4; i < n; i += gridDim.x * 256 * 4) {
        float4 v = *(const float4*)(W + i);
        m = fmaxf(m, fmaxf(fmaxf(fabsf(v.x), fabsf(v.y)),
                           fmaxf(fabsf(v.z), fabsf(v.w))));
    }
    red[tid] = m; __syncthreads();
    for (int s = 128; s > 0; s >>= 1) {
        if (tid < s) red[tid] = fmaxf(red[tid], red[tid + s]);
        __syncthreads();
    }
    if (tid == 0) bmax[blockIdx.x] = red[0];
}

// ---------------- pass 0b: ws = max|W| / 127 -------------------------------
__global__ void wmax2_kernel(const float* __restrict__ bmax,
                             float* __restrict__ ws) {
    __shared__ float red[1024];
    int tid = threadIdx.x;
    red[tid] = bmax[tid]; __syncthreads();
    for (int s = 512; s > 0; s >>= 1) {
        if (tid < s) red[tid] = fmaxf(red[tid], red[tid + s]);
        __syncthreads();
    }
    if (tid == 0) ws[0] = red[0] * (1.0f / 127.0f);
}

// ---------------- pass 1: quantize x -> int8 (scalar maxabs) ---------------
__global__ void quant_x_kernel(const float* __restrict__ x,
                               char* __restrict__ xq,
                               const float* __restrict__ xscale, int n) {
    int i = (blockIdx.x * blockDim.x + threadIdx.x) * 4;
    if (i >= n) return;
    float inv = 127.0f / fmaxf(xscale[0], 1e-8f);
    float4 v = *(const float4*)(x + i);
    char4 o;
    o.x = (char)fminf(fmaxf(rintf(v.x * inv), -127.f), 127.f);
    o.y = (char)fminf(fmaxf(rintf(v.y * inv), -127.f), 127.f);
    o.z = (char)fminf(fmaxf(rintf(v.z * inv), -127.f), 127.f);
    o.w = (char)fminf(fmaxf(rintf(v.w * inv), -127.f), 127.f);
    *(char4*)(xq + i) = o;
}

// ---------------- pass 2: W (K x N) -> int8 transposed Wt (N x K) ----------
// W values are exact multiples of ws; rint(W/ws) recovers the int8 code.
__global__ void convW_kernel(const float* __restrict__ W,
                             char* __restrict__ Wt,
                             const float* __restrict__ ws) {
    __shared__ float tile[32][33];
    float invws = 1.0f / ws[0];
    int n0 = blockIdx.x * 32, k0 = blockIdx.y * 32;
    tile[threadIdx.y][threadIdx.x] =
        W[(size_t)(k0 + threadIdx.y) * D_OUT + n0 + threadIdx.x];
    __syncthreads();
    Wt[(size_t)(n0 + threadIdx.y) * D_IN + k0 + threadIdx.x] =
        (char)rintf(tile[threadIdx.x][threadIdx.y] * invws);
}

// ---------------- pass 3: 256x256 int8 GEMM, 2-region K-tile ---------------
// A : [M][K] i8, Bt : [N][K] i8, C : [M][N] f32 = i32acc * (sx*ws) + bias.
// BK = 128 i8 elems = 128 B rows -> ALL byte addressing (swizzle, staging
// offsets, vmcnt counts) identical to the verified bf16 kernel; NT = 32.
//  R1 (compute): barrier | STAGE B1(t+1)->nxt | ds_read b01,a03,b23 | Q1,Q2
//                | ds_read a47 (reuse regs) | Q3,Q4
//  R2 (publish): barrier | STAGE B0(t+2),A(t+2)->cur | s_waitcnt vmcnt(6)
// vmcnt(6) leaves exactly {B0(t+2),A(t+2)}: tile t+1 fully resident.
__global__ __launch_bounds__(512, 2)
void gemm_kernel(const char* __restrict__ A,
                 const char* __restrict__ Bt,
                 const float* __restrict__ bias,
                 const float* __restrict__ xscale,
                 const float* __restrict__ wsp,
                 float* __restrict__ C, int M) {
    constexpr int K = D_IN, N = D_OUT;         // byte stride per row = K (i8)
    constexpr int NT = K / 128;                // 32 K-tiles of 128 elems
    __shared__ char lds[2 * 65536];            // 2 x (A 32KiB + B 32KiB)

    const int tid  = threadIdx.x;
    const int lane = tid & 63;
    const int wid  = tid >> 6;
    const int wr   = wid >> 2;                 // 0..1  (M)
    const int wc   = wid & 3;                  // 0..3  (N)

    // bijective XCD-aware block swizzle
    const int nTn = N / 256;
    const int nwg = gridDim.x;
    int bid = blockIdx.x;
    int q8 = nwg >> 3, r8 = nwg & 7;
    int xcd = bid & 7, idx = bid >> 3;
    int swz = (xcd < r8 ? xcd * (q8 + 1) : r8 * (q8 + 1) + (xcd - r8) * q8) + idx;
    const int tm = swz / nTn, tn = swz % nTn;
    const int row0 = tm * 256, col0 = tn * 256;

    // staging: LDS dest LINEAR; XOR involution sw = p ^ ((p>>7)&7)<<4 applied
    // to the global SOURCE address, matched by swizzled ds_reads.
    int srcOff[4], dstOff[4];
#pragma unroll
    for (int i = 0; i < 4; ++i) {
        int p  = (i * 512 + tid) * 16;
        int sw = p ^ (((p >> 7) & 7) << 4);
        dstOff[i] = p;
        srcOff[i] = (sw >> 7) * K + (sw & 127);
    }

    const char* srcA = A  + (size_t)row0 * K;
    const char* srcB = Bt + (size_t)col0 * K;
    char* ldsb = lds;

    auto STAGE4 = [&](const char* src, char* dst) {
#pragma unroll
        for (int i = 0; i < 4; ++i)
            __builtin_amdgcn_global_load_lds((g_u32*)(src + srcOff[i]),
                                             (l_u32*)(dst + dstOff[i]), 16, 0, 0);
    };
    auto STAGE2 = [&](const char* src, char* dst) {
#pragma unroll
        for (int i = 0; i < 2; ++i)
            __builtin_amdgcn_global_load_lds((g_u32*)(src + srcOff[i]),
                                             (l_u32*)(dst + dstOff[i]), 16, 0, 0);
    };

    // ---- prologue: tile0 full (8 loads) + tile1 {B0, A} (6 loads) ----
    STAGE2(srcB, ldsb + 32768);                        // B0(0) -> buf0
    STAGE4(srcA, ldsb);                                // A(0)  -> buf0
    STAGE2(srcB + 128 * K, ldsb + 32768 + 16384);      // B1(0) -> buf0
    STAGE2(srcB + 128,     ldsb + 65536 + 32768);      // B0(1) -> buf1
    STAGE4(srcA + 128,     ldsb + 65536);              // A(1)  -> buf1

    i32x4 acc[8][4];
#pragma unroll
    for (int m = 0; m < 8; ++m)
#pragma unroll
        for (int n = 0; n < 4; ++n) acc[m][n] = (i32x4){0, 0, 0, 0};

    // swizzled per-lane read bases (row&7 == lane&7 for all fragment rows)
    const int cp0 = (((lane >> 4) << 4)) ^ ((lane & 7) << 4);
    const int cp1 = cp0 ^ 64;                          // k-half 1
    const int aBase = (wr * 128 + (lane & 15)) * 128;
    const int bBase = (wc * 64  + (lane & 15)) * 128;

    asm volatile("s_waitcnt vmcnt(6)" ::: "memory");   // tile0 resident

    auto KITER = [&](int t, char* cur, char* nxt) {
        i32x4 a[4][2], b01[2][2], b23[2][2];
        const char* cA = cur;
        const char* cB = cur + 32768;

        // ================= region 1: compute =================
        __builtin_amdgcn_s_barrier();
        if (t + 1 < NT) STAGE2(srcB + 128 * K + (t + 1) * 128, nxt + 32768 + 16384);

#pragma unroll
        for (int n = 0; n < 2; ++n) {
            b01[n][0] = *(const i32x4*)(cB + bBase + n * 2048 + cp0);
            b01[n][1] = *(const i32x4*)(cB + bBase + n * 2048 + cp1);
        }
#pragma unroll
        for (int m = 0; m < 4; ++m) {
            a[m][0] = *(const i32x4*)(cA + aBase + m * 2048 + cp0);
            a[m][1] = *(const i32x4*)(cA + aBase + m * 2048 + cp1);
        }
#pragma unroll
        for (int n = 0; n < 2; ++n) {
            b23[n][0] = *(const i32x4*)(cB + bBase + 4096 + n * 2048 + cp0);
            b23[n][1] = *(const i32x4*)(cB + bBase + 4096 + n * 2048 + cp1);
        }

        __builtin_amdgcn_s_setprio(1);
        // Q1: (m0-3, n0-1)
#pragma unroll
        for (int m = 0; m < 4; ++m)
#pragma unroll
            for (int n = 0; n < 2; ++n) {
                acc[m][n] = __builtin_amdgcn_mfma_i32_16x16x64_i8(a[m][0], b01[n][0], acc[m][n], 0, 0, 0);
                acc[m][n] = __builtin_amdgcn_mfma_i32_16x16x64_i8(a[m][1], b01[n][1], acc[m][n], 0, 0, 0);
            }
        // Q2: (m0-3, n2-3)
#pragma unroll
        for (int m = 0; m < 4; ++m)
#pragma unroll
            for (int n = 0; n < 2; ++n) {
                acc[m][n + 2] = __builtin_amdgcn_mfma_i32_16x16x64_i8(a[m][0], b23[n][0], acc[m][n + 2], 0, 0, 0);
                acc[m][n + 2] = __builtin_amdgcn_mfma_i32_16x16x64_i8(a[m][1], b23[n][1], acc[m][n + 2], 0, 0, 0);
            }
        // reload A rows 4-7 (reuse registers)
#pragma unroll
        for (int m = 0; m < 4; ++m) {
            a[m][0] = *(const i32x4*)(cA + aBase + 8192 + m * 2048 + cp0);
            a[m][1] = *(const i32x4*)(cA + aBase + 8192 + m * 2048 + cp1);
        }
        // Q3: (m4-7, n2-3)
#pragma unroll
        for (int m = 0; m < 4; ++m)
#pragma unroll
            for (int n = 0; n < 2; ++n) {
                acc[m + 4][n + 2] = __builtin_amdgcn_mfma_i32_16x16x64_i8(a[m][0], b23[n][0], acc[m + 4][n + 2], 0, 0, 0);
                acc[m + 4][n + 2] = __builtin_amdgcn_mfma_i32_16x16x64_i8(a[m][1], b23[n][1], acc[m + 4][n + 2], 0, 0, 0);
            }
        // Q4: (m4-7, n0-1)
#pragma unroll
        for (int m = 0; m < 4; ++m)
#pragma unroll
            for (int n = 0; n < 2; ++n) {
                acc[m + 4][n] = __builtin_amdgcn_mfma_i32_16x16x64_i8(a[m][0], b01[n][0], acc[m + 4][n], 0, 0, 0);
                acc[m + 4][n] = __builtin_amdgcn_mfma_i32_16x16x64_i8(a[m][1], b01[n][1], acc[m + 4][n], 0, 0, 0);
            }
        __builtin_amdgcn_s_setprio(0);

        // ================= region 2: publish =================
        __builtin_amdgcn_s_barrier();
        if (t + 2 < NT) {
            STAGE2(srcB + (t + 2) * 128, cur + 32768);     // B0(t+2) -> cur
            STAGE4(srcA + (t + 2) * 128, cur);             // A (t+2) -> cur
            asm volatile("s_waitcnt vmcnt(6)" ::: "memory");
        } else {
            asm volatile("s_waitcnt vmcnt(0)" ::: "memory");
        }
    };

    for (int t = 0; t < NT; t += 2) {
        KITER(t,     ldsb,         ldsb + 65536);
        KITER(t + 1, ldsb + 65536, ldsb);
    }

    // ---- epilogue: C = acc * (sx*ws) + bias ----
    const float scale = (fmaxf(xscale[0], 1e-8f) * (1.0f / 127.0f)) * wsp[0];
    const int lr = (lane >> 4) * 4, lc = lane & 15;
#pragma unroll
    for (int n = 0; n < 4; ++n) {
        int col = col0 + wc * 64 + n * 16 + lc;
        float bv = bias[col];
#pragma unroll
        for (int m = 0; m < 8; ++m) {
            int rowb = row0 + wr * 128 + m * 16 + lr;
            i32x4 v = acc[m][n];
#pragma unroll
            for (int r2 = 0; r2 < 4; ++r2)
                C[(size_t)(rowb + r2) * N + col] = (float)v[r2] * scale + bv;
        }
    }
}

extern "C" void kernel_launch(void* const* d_in, const int* in_sizes, int n_in,
                              void* d_out, int out_size, void* d_ws, size_t ws_size,
                              hipStream_t stream) {
    const float* x      = (const float*)d_in[0];   // [4,2048,4096] f32
    const float* W      = (const float*)d_in[1];   // [4096,4096] f32
    const float* xscale = (const float*)d_in[2];   // scalar
    const float* bias   = (const float*)d_in[3];   // [4096] f32
    float* out = (float*)d_out;

    const int nx = in_sizes[0];            // 33554432
    const int nw = in_sizes[1];            // 16777216
    const int M  = nx / D_IN;              // 8192

    char*  xq   = (char*)d_ws;                                  // 32 MiB
    char*  Wt   = (char*)d_ws + (size_t)nx;                     // 16 MiB
    float* bmax = (float*)((char*)d_ws + (size_t)nx + nw);      // 4 KiB
    float* wsp  = bmax + 1024;                                  // 4 B

    wmax1_kernel<<<1024, 256, 0, stream>>>(W, bmax, nw);
    wmax2_kernel<<<1, 1024, 0, stream>>>(bmax, wsp);

    quant_x_kernel<<<nx / 4 / 256, 256, 0, stream>>>(x, xq, xscale, nx);

    dim3 tb(32, 32);
    dim3 tg(D_OUT / 32, D_IN / 32);
    convW_kernel<<<tg, tb, 0, stream>>>(W, Wt, wsp);

    int grid = (M / 256) * (D_OUT / 256);  // 512
    gemm_kernel<<<grid, 512, 0, stream>>>(xq, Wt, bias, xscale, wsp, out, M);
}